// Round 26
// baseline (361.340 us; speedup 1.0000x reference)
//
#include <hip/hip_runtime.h>

#define B_ 32
#define L_ 256
#define D_ 768
#define H_ 12
#define DK_ 64
#define MEM_ 384

typedef __attribute__((ext_vector_type(8))) short bfrag8;    // 8 bf16 (4 VGPRs)
typedef __attribute__((ext_vector_type(8))) unsigned short us8;
typedef __attribute__((ext_vector_type(4))) float f32x4;

__device__ inline unsigned short f2bf(float f) {
  unsigned u = __float_as_uint(f);
  return (unsigned short)((u + 0x7fffu + ((u >> 16) & 1u)) >> 16);
}
__device__ inline float bf2f(unsigned short u) {
  return __uint_as_float(((unsigned)u) << 16);
}
__device__ inline float tanh_fast(float x) {
  x = fminf(fmaxf(x, -30.f), 30.f);
  float e = __expf(2.f * x);
  return (e - 1.f) * __builtin_amdgcn_rcpf(e + 1.f);
}
__device__ inline void gload_lds16(const unsigned short* g, unsigned short* l) {
  __builtin_amdgcn_global_load_lds(
      (__attribute__((address_space(1))) void*)(g),
      (__attribute__((address_space(3))) void*)(l), 16, 0, 0);
}

// ---------------- block reduce helpers ----------------
__device__ inline float waveRedSum(float v) {
#pragma unroll
  for (int o = 32; o; o >>= 1) v += __shfl_xor(v, o, 64);
  return v;
}
__device__ inline float blkRedSum(float v, float* red) {
  v = waveRedSum(v);
  int w = threadIdx.x >> 6;
  __syncthreads();
  if ((threadIdx.x & 63) == 0) red[w] = v;
  __syncthreads();
  return red[0] + red[1] + red[2] + red[3];
}

// ---------------- prep: all weight transposes (blocks 0..599) + LayerNorm (600+) -----
// (fp32 x output removed — it was a dead store; only xbf is consumed downstream)
__global__ __launch_bounds__(256) void prep_kernel(
    const float* __restrict__ seq, const float* __restrict__ lng,
    const float* __restrict__ lnb,
    unsigned short* __restrict__ xbf,
    const float* __restrict__ wq, unsigned short* __restrict__ wqT,
    const float* __restrict__ wk, unsigned short* __restrict__ wkT,
    const float* __restrict__ wa0, unsigned short* __restrict__ wa0T,
    const float* __restrict__ ws0, unsigned short* __restrict__ ws0T,
    const float* __restrict__ wa1, unsigned short* __restrict__ wa1T,
    const float* __restrict__ ws1, unsigned short* __restrict__ ws1T,
    const float* __restrict__ aff1, unsigned short* __restrict__ aff1T,
    const float* __restrict__ aff2, unsigned short* __restrict__ aff2T,
    const float* __restrict__ wd, unsigned short* __restrict__ wdT,
    const float* __restrict__ wm, unsigned short* __restrict__ wmT) {
  int bid = blockIdx.x;
  if (bid >= 600) {  // ---- LayerNorm row ----
    long row = bid - 600;
    const float* p = seq + row * D_;
    float v[3];
#pragma unroll
    for (int i = 0; i < 3; ++i) v[i] = p[threadIdx.x + i * 256];
    __shared__ float red[4];
    float s = v[0] + v[1] + v[2];
    s = blkRedSum(s, red);
    float mu = s * (1.f / D_);
    float ss = 0.f;
#pragma unroll
    for (int i = 0; i < 3; ++i) { float d = v[i] - mu; ss += d * d; }
    ss = blkRedSum(ss, red);
    float sd = sqrtf(ss * (1.f / (D_ - 1)));
    float inv = 1.f / (sd + 1e-6f);
#pragma unroll
    for (int i = 0; i < 3; ++i) {
      int c = threadIdx.x + i * 256;
      float o = lng[c] * (v[i] - mu) * inv + lnb[c];
      xbf[row * D_ + c] = f2bf(o);
    }
    return;
  }
  const float* src; unsigned short* dst; int Rr, Cc, tIdx;
  if (bid < 144)      { src = wq;   dst = wqT;   Rr = 768; Cc = 768; tIdx = bid; }
  else if (bid < 288) { src = wk;   dst = wkT;   Rr = 768; Cc = 768; tIdx = bid - 144; }
  else if (bid < 360) { src = wa0;  dst = wa0T;  Rr = 768; Cc = 384; tIdx = bid - 288; }
  else if (bid < 432) { src = ws0;  dst = ws0T;  Rr = 768; Cc = 384; tIdx = bid - 360; }
  else if (bid < 468) { src = wa1;  dst = wa1T;  Rr = 384; Cc = 384; tIdx = bid - 432; }
  else if (bid < 504) { src = ws1;  dst = ws1T;  Rr = 384; Cc = 384; tIdx = bid - 468; }
  else if (bid < 540) { src = aff1; dst = aff1T; Rr = 384; Cc = 384; tIdx = bid - 504; }
  else if (bid < 576) { src = aff2; dst = aff2T; Rr = 384; Cc = 384; tIdx = bid - 540; }
  else if (bid < 588) { src = wd;   dst = wdT;   Rr = 768; Cc = 64;  tIdx = bid - 576; }
  else { int h = bid - 588; src = wm + h * 4096; dst = wmT + h * 4096; Rr = 64; Cc = 64; tIdx = 0; }
  __shared__ float tile[64][65];
  int nx = Cc >> 6;
  int c0 = (tIdx % nx) * 64, r0 = (tIdx / nx) * 64;
  int tx = threadIdx.x & 63, ty = threadIdx.x >> 6;
#pragma unroll
  for (int i = 0; i < 16; ++i)
    tile[ty + i * 4][tx] = src[(long)(r0 + ty + i * 4) * Cc + c0 + tx];
  __syncthreads();
#pragma unroll
  for (int i = 0; i < 16; ++i)
    dst[(long)(c0 + ty + i * 4) * Rr + r0 + tx] = f2bf(tile[tx][ty + i * 4]);
}

// ---------------- all-bf16 MFMA GEMM, DMA staging, BK=32*KCH, dbuf + counted vmcnt ---
// KCH k-chunks per buffer (each chunk = proven [A 64/128x32 | B 128x32] layout).
// 1D grid with XCD-aware remap (gmode 0: group blocks sharing bm; 1: sharing bz).
template <int MR, int KCH>
__global__ __launch_bounds__(256) void gemm_bb(
    const unsigned short* __restrict__ A, const unsigned short* __restrict__ Bt,
    float* __restrict__ C, unsigned short* __restrict__ Cbf,
    unsigned short* __restrict__ CT,
    int M, int N, int K, long sA, long sB, long sC, long sCT,
    const float* __restrict__ bias, const float* __restrict__ rowDiv, int relu,
    const unsigned short* __restrict__ A2, const unsigned short* __restrict__ Bt2,
    float* __restrict__ C2, unsigned short* __restrict__ Cbf2,
    unsigned short* __restrict__ CT2,
    const float* __restrict__ bias2, const float* __restrict__ rowDiv2, int zsplit,
    int GX, int GZ, int gmode) {
  constexpr int MFRAG = MR / 32;
  constexpr int RW = MR / 2;
  constexpr int ASH = MR * 32;
  constexpr int CHS = ASH + 4096;
  constexpr int BUFS = KCH * CHS;
  constexpr int TSH = 64 * (MR + 8);
  constexpr int SMN = (2 * BUFS > TSH) ? 2 * BUFS : TSH;
  constexpr int LPI = KCH * (MR / 64 + 2);  // loads per iteration
  __shared__ alignas(16) unsigned short smem[SMN];
  const int tid = threadIdx.x;
  int dtot = blockIdx.x;
  int xcd = dtot & 7, rrg = dtot >> 3;
  int bn, bm, bz;
  if (gmode == 0) {
    int gsz = GX * GZ;
    int ul = rrg / gsz, j = rrg % gsz;
    bm = ul * 8 + xcd;
    bz = j / GX;
    bn = j % GX;
  } else {
    int gsz2 = GX * GZ;   // GZ carries bm-count here
    int ul = rrg / gsz2, j = rrg % gsz2;
    bz = ul * 8 + xcd;
    bm = j / GX;
    bn = j % GX;
  }
  const unsigned short* Ap = A; const unsigned short* Btp = Bt;
  float* Cp = C; unsigned short* Cbp = Cbf; unsigned short* CTp = CT;
  const float* biasp = bias; const float* rowDivp = rowDiv;
  if (zsplit > 0 && bz >= zsplit) {
    bz -= zsplit;
    Ap = A2; Btp = Bt2; Cp = C2; Cbp = Cbf2; CTp = CT2; biasp = bias2; rowDivp = rowDiv2;
  }
  Ap += (long)bz * sA; Btp += (long)bz * sB;
  if (Cp) Cp += (long)bz * sC;
  if (Cbp) Cbp += (long)bz * sC;
  if (CTp) CTp += (long)bz * sCT;

  f32x4 acc[MFRAG][4] = {};
  const int l = tid & 63, w = tid >> 6;
  const int wr = w >> 1, wc = w & 1;
  const int lr = l & 15, sg = l >> 4;

  const int rc = l >> 2;
  const int sslot = (l & 3) ^ ((rc >> 1) & 3);
  const unsigned short* gA0 = Ap + (long)(bm * MR + w * 16 + rc) * K + sslot * 8;
  const unsigned short* gA1 = (MR == 128)
      ? Ap + (long)(bm * MR + (w + 4) * 16 + rc) * K + sslot * 8 : nullptr;
  const unsigned short* gB0 = Btp + (long)(bn * 128 + w * 16 + rc) * K + sslot * 8;
  const unsigned short* gB1 = Btp + (long)(bn * 128 + (w + 4) * 16 + rc) * K + sslot * 8;
  const int stA0 = w * 512, stA1 = (w + 4) * 512;
  const int stB0 = ASH + w * 512, stB1 = ASH + (w + 4) * 512;

  const int swz = (sg ^ ((lr >> 1) & 3)) * 8;
  int aoff[MFRAG], boff[4];
#pragma unroll
  for (int m = 0; m < MFRAG; ++m) aoff[m] = (wr * RW + m * 16 + lr) * 32 + swz;
#pragma unroll
  for (int n = 0; n < 4; ++n) boff[n] = ASH + (wc * 64 + n * 16 + lr) * 32 + swz;

  auto stage = [&](int kbase, unsigned short* buf) {
#pragma unroll
    for (int c = 0; c < KCH; ++c) {
      gload_lds16(gA0 + kbase + c * 32, buf + c * CHS + stA0);
      if (MR == 128) gload_lds16(gA1 + kbase + c * 32, buf + c * CHS + stA1);
      gload_lds16(gB0 + kbase + c * 32, buf + c * CHS + stB0);
      gload_lds16(gB1 + kbase + c * 32, buf + c * CHS + stB1);
    }
  };

  const int nt = K / (32 * KCH);
  stage(0, smem);

  for (int t = 0; t < nt; ++t) {
    const int cur = (t & 1) * BUFS;
    if (t + 1 < nt) {
      stage((t + 1) * (32 * KCH), smem + ((t + 1) & 1) * BUFS);
      if constexpr (LPI == 3)
        asm volatile("s_waitcnt vmcnt(3)" ::: "memory");
      else if constexpr (LPI == 4)
        asm volatile("s_waitcnt vmcnt(4)" ::: "memory");
      else if constexpr (LPI == 6)
        asm volatile("s_waitcnt vmcnt(6)" ::: "memory");
      else
        asm volatile("s_waitcnt vmcnt(8)" ::: "memory");
    } else {
      asm volatile("s_waitcnt vmcnt(0)" ::: "memory");
    }
    __builtin_amdgcn_s_barrier();
    asm volatile("" ::: "memory");
    bfrag8 af[KCH][MFRAG], bf[KCH][4];
#pragma unroll
    for (int c = 0; c < KCH; ++c) {
#pragma unroll
      for (int m = 0; m < MFRAG; ++m)
        af[c][m] = *(const bfrag8*)(smem + cur + c * CHS + aoff[m]);
#pragma unroll
      for (int n = 0; n < 4; ++n)
        bf[c][n] = *(const bfrag8*)(smem + cur + c * CHS + boff[n]);
    }
    __builtin_amdgcn_s_setprio(1);
#pragma unroll
    for (int c = 0; c < KCH; ++c)
#pragma unroll
      for (int m = 0; m < MFRAG; ++m)
#pragma unroll
        for (int n = 0; n < 4; ++n)
          acc[m][n] = __builtin_amdgcn_mfma_f32_16x16x32_bf16(af[c][m], bf[c][n], acc[m][n], 0, 0, 0);
    __builtin_amdgcn_s_setprio(0);
    asm volatile("" ::: "memory");
    __builtin_amdgcn_s_barrier();
    asm volatile("" ::: "memory");
  }

  if (Cp || Cbp) {
#pragma unroll
    for (int m = 0; m < MFRAG; ++m) {
#pragma unroll
      for (int r = 0; r < 4; ++r) {
        int row = bm * MR + wr * RW + m * 16 + (l >> 4) * 4 + r;
        float rd = rowDivp ? 1.f / rowDivp[(long)bz * M + row] : 1.f;
#pragma unroll
        for (int n = 0; n < 4; ++n) {
          int col = bn * 128 + wc * 64 + n * 16 + lr;
          float v = acc[m][n][r];
          if (biasp) v += biasp[col];
          v *= rd;
          if (relu) v = fmaxf(v, 0.f);
          if (Cp) Cp[(long)row * N + col] = v;
          if (Cbp) Cbp[(long)row * N + col] = f2bf(v);
        }
      }
    }
  }
  if (CT) {
    auto Ts = (unsigned short(*)[MR + 8])smem;
#pragma unroll
    for (int ch = 0; ch < 2; ++ch) {
      __syncthreads();
      if (wc == ch) {
#pragma unroll
        for (int m = 0; m < MFRAG; ++m) {
#pragma unroll
          for (int r = 0; r < 4; ++r) {
            int rowl = wr * RW + m * 16 + (l >> 4) * 4 + r;
            float rd = rowDivp ? 1.f / rowDivp[(long)bz * M + bm * MR + rowl] : 1.f;
#pragma unroll
            for (int n = 0; n < 4; ++n) {
              int col = bn * 128 + wc * 64 + n * 16 + lr;
              float v = acc[m][n][r];
              if (biasp) v += biasp[col];
              v *= rd;
              if (relu) v = fmaxf(v, 0.f);
              Ts[n * 16 + lr][rowl] = f2bf(v);
            }
          }
        }
      }
      __syncthreads();
      int trow = tid >> 2, tc = (tid & 3) * (MR / 4);
      int colg = bn * 128 + ch * 64 + trow;
      int rowg = bm * MR + tc;
      unsigned short* dp = CTp + (long)(rowg >> 8) * sCT + (long)colg * 256 + (rowg & 255);
#pragma unroll
      for (int j = 0; j < MR / 32; ++j)
        *(us8*)(dp + j * 8) = *(const us8*)&Ts[trow][tc + j * 8];
    }
  }
}

// ---------------- attention halves (0..1023, XCD-grouped, no-max softmax,
//                  next-pair k/q prefetched under softmax tail) + asp (1024..1535) ----
__global__ __launch_bounds__(256) void attn_asp(
    const unsigned short* __restrict__ qbf, const unsigned short* __restrict__ kbf,
    const float* __restrict__ srcm,
    float* __restrict__ part0, float* __restrict__ part1,
    const unsigned short* __restrict__ xbf, const unsigned short* __restrict__ wdT,
    const float* __restrict__ amask, const float* __restrict__ bd,
    unsigned short* __restrict__ aspbf) {
  int t = threadIdx.x;
  int w = t >> 6, l = t & 63;
  int lr = l & 15, kg = (l >> 4) * 8;
  if (blockIdx.x >= 1024) {  // ---- asp projection ----
    int l0 = (blockIdx.x - 1024) << 4;
    const unsigned short* ap = xbf + (long)(l0 + lr) * D_ + kg;
    const unsigned short* bp = wdT + (long)(w * 16 + lr) * D_ + kg;
    f32x4 acc = {};
#pragma unroll
    for (int k0 = 0; k0 < D_; k0 += 32) {
      bfrag8 af = *(const bfrag8*)(ap + k0);
      bfrag8 bf = *(const bfrag8*)(bp + k0);
      acc = __builtin_amdgcn_mfma_f32_16x16x32_bf16(af, bf, acc, 0, 0, 0);
    }
    int col = w * 16 + lr;
#pragma unroll
    for (int r = 0; r < 4; ++r) {
      int row = l0 + (l >> 4) * 4 + r;
      float v = acc[r] * amask[row] + bd[col];
      aspbf[(long)row * DK_ + col] = f2bf(v);
    }
    return;
  }
  int d = blockIdx.x;
  int b = (d & 7) + 8 * ((d >> 3) & 3);
  int rest = d >> 5;
  int l0 = (rest & 15) << 4;
  int half = rest >> 4;
  int rbase = (l >> 4) * 4;
  __shared__ float red[3][2][16][4];
  float acc[4][4] = {};
  float cmv[4];
#pragma unroll
  for (int ct = 0; ct < 4; ++ct) cmv[ct] = srcm[b * L_ + w * 64 + ct * 16 + lr];

  const int hp0 = half * 3;
  const long qrow = (long)b * L_ + l0 + lr;
  const unsigned short* apq = qbf + qrow * D_ + hp0 * 128 + kg;
  bfrag8 a00 = *(const bfrag8*)apq;
  bfrag8 a01 = *(const bfrag8*)(apq + 32);
  bfrag8 a10 = *(const bfrag8*)(apq + 64);
  bfrag8 a11 = *(const bfrag8*)(apq + 96);
  bfrag8 kv[4][4];
#pragma unroll
  for (int ct = 0; ct < 4; ++ct) {
    const unsigned short* bp =
        kbf + ((long)b * L_ + w * 64 + ct * 16 + lr) * D_ + hp0 * 128 + kg;
    kv[ct][0] = *(const bfrag8*)bp;
    kv[ct][1] = *(const bfrag8*)(bp + 32);
    kv[ct][2] = *(const bfrag8*)(bp + 64);
    kv[ct][3] = *(const bfrag8*)(bp + 96);
  }

#pragma unroll 1
  for (int ph = 0; ph < 3; ++ph) {
    float sv0[4][4], sv1[4][4];
#pragma unroll
    for (int ct = 0; ct < 4; ++ct) {
      f32x4 c0 = {}, c1 = {};
      c0 = __builtin_amdgcn_mfma_f32_16x16x32_bf16(a00, kv[ct][0], c0, 0, 0, 0);
      c0 = __builtin_amdgcn_mfma_f32_16x16x32_bf16(a01, kv[ct][1], c0, 0, 0, 0);
      c1 = __builtin_amdgcn_mfma_f32_16x16x32_bf16(a10, kv[ct][2], c1, 0, 0, 0);
      c1 = __builtin_amdgcn_mfma_f32_16x16x32_bf16(a11, kv[ct][3], c1, 0, 0, 0);
#pragma unroll
      for (int r = 0; r < 4; ++r) { sv0[ct][r] = c0[r]; sv1[ct][r] = c1[r]; }
    }
    if (ph < 2) {
      const unsigned short* apn = qbf + qrow * D_ + (hp0 + ph + 1) * 128 + kg;
      a00 = *(const bfrag8*)apn;
      a01 = *(const bfrag8*)(apn + 32);
      a10 = *(const bfrag8*)(apn + 64);
      a11 = *(const bfrag8*)(apn + 96);
#pragma unroll
      for (int ct = 0; ct < 4; ++ct) {
        const unsigned short* bp =
            kbf + ((long)b * L_ + w * 64 + ct * 16 + lr) * D_ + (hp0 + ph + 1) * 128 + kg;
        kv[ct][0] = *(const bfrag8*)bp;
        kv[ct][1] = *(const bfrag8*)(bp + 32);
        kv[ct][2] = *(const bfrag8*)(bp + 64);
        kv[ct][3] = *(const bfrag8*)(bp + 96);
      }
    }
#pragma unroll
    for (int ct = 0; ct < 4; ++ct) {
      bool msk = (cmv[ct] == 0.f);
#pragma unroll
      for (int r = 0; r < 4; ++r) {
        sv0[ct][r] = __expf(msk ? -1e9f : sv0[ct][r] * 0.125f);
        sv1[ct][r] = __expf(msk ? -1e9f : sv1[ct][r] * 0.125f);
      }
    }
#pragma unroll
    for (int r = 0; r < 4; ++r) {
      float s0 = sv0[0][r] + sv0[1][r] + sv0[2][r] + sv0[3][r];
      float s1 = sv1[0][r] + sv1[1][r] + sv1[2][r] + sv1[3][r];
#pragma unroll
      for (int o = 1; o < 16; o <<= 1) {
        s0 += __shfl_xor(s0, o, 64);
        s1 += __shfl_xor(s1, o, 64);
      }
      if (lr == 0) {
        red[ph][0][rbase + r][w] = s0;
        red[ph][1][rbase + r][w] = s1;
      }
    }
    __syncthreads();
#pragma unroll
    for (int r = 0; r < 4; ++r) {
      f32x4 s4 = *(const f32x4*)&red[ph][0][rbase + r][0];
      float inv0 = __builtin_amdgcn_rcpf(s4[0] + s4[1] + s4[2] + s4[3] + 1e-30f);
      f32x4 t4 = *(const f32x4*)&red[ph][1][rbase + r][0];
      float inv1 = __builtin_amdgcn_rcpf(t4[0] + t4[1] + t4[2] + t4[3] + 1e-30f);
#pragma unroll
      for (int ct = 0; ct < 4; ++ct)
        acc[ct][r] += sv0[ct][r] * inv0 + sv1[ct][r] * inv1;
    }
  }

  float* pp = half ? part1 : part0;
#pragma unroll
  for (int r = 0; r < 4; ++r) {
    int row = l0 + rbase + r;
#pragma unroll
    for (int ct = 0; ct < 4; ++ct) {
      int col = w * 64 + ct * 16 + lr;
      pp[((long)b * L_ + row) * L_ + col] = acc[ct][r];
    }
  }
}

// ---------------- fused: tmp[16x64] = asp16 @ Wm[h] (in-LDS), then
//                  asps_mean row-block + avgH atomic partial sums ----------------
__global__ __launch_bounds__(256) void asp_wm_mean(
    const unsigned short* __restrict__ aspbf,
    const unsigned short* __restrict__ wmT,
    const unsigned short* __restrict__ kbf,
    const float* __restrict__ bias_m,
    float* __restrict__ asps_mean, float* __restrict__ avgH) {
  int blk = blockIdx.x;
  int b = blk >> 4, l0 = (blk & 15) << 4;
  int t = threadIdx.x;
  int w = t >> 6, l = t & 63;
  int lr = l & 15, sg = l >> 4, kg = sg * 8;
  float bm = bias_m[0];
  __shared__ unsigned short Ts[16][72];
  // A rows are h-independent: load once (rows l0+lr, cols kg.. of 64)
  const unsigned short* ap = aspbf + (long)(b * L_ + l0 + lr) * DK_ + kg;
  bfrag8 aA0 = *(const bfrag8*)ap;
  bfrag8 aA1 = *(const bfrag8*)(ap + 32);
  float accg[4][4] = {};
  for (int h = 0; h < H_; ++h) {
    const unsigned short* wp = wmT + h * 4096;
    // tmp = asp16 @ Wm[h]: every wave computes all 4 n-frags (redundant, cheap);
    // wave 0 publishes bf16 tmp to LDS (same rounding as the old tmpA path).
    f32x4 uacc[4] = {};
#pragma unroll
    for (int n = 0; n < 4; ++n) {
      bfrag8 b0 = *(const bfrag8*)(wp + (n * 16 + lr) * 64 + kg);
      bfrag8 b1 = *(const bfrag8*)(wp + (n * 16 + lr) * 64 + 32 + kg);
      uacc[n] = __builtin_amdgcn_mfma_f32_16x16x32_bf16(aA0, b0, uacc[n], 0, 0, 0);
      uacc[n] = __builtin_amdgcn_mfma_f32_16x16x32_bf16(aA1, b1, uacc[n], 0, 0, 0);
    }
    if (w == 0) {
#pragma unroll
      for (int n = 0; n < 4; ++n)
#pragma unroll
        for (int r = 0; r < 4; ++r)
          Ts[sg * 4 + r][n * 16 + lr] = f2bf(uacc[n][r]);
    }
    __syncthreads();
    bfrag8 af0 = *(const bfrag8*)&Ts[lr][kg];
    bfrag8 af1 = *(const bfrag8*)&Ts[lr][32 + kg];
#pragma unroll
    for (int ct = 0; ct < 4; ++ct) {
      const unsigned short* bp =
          kbf + ((long)b * L_ + w * 64 + ct * 16 + lr) * D_ + h * 64 + kg;
      bfrag8 bf0 = *(const bfrag8*)bp;
      bfrag8 bf1 = *(const bfrag8*)(bp + 32);
      f32x4 accl = {};
      accl = __builtin_amdgcn_mfma_f32_16x16x32_bf16(af0, bf0, accl, 0, 0, 0);
      accl = __builtin_amdgcn_mfma_f32_16x16x32_bf16(af1, bf1, accl, 0, 0, 0);
#pragma unroll
      for (int r = 0; r < 4; ++r) accg[ct][r] += tanh_fast(accl[r] + bm);
    }
    __syncthreads();  // WAR on Ts before next h
  }
#pragma unroll
  for (int ct = 0; ct < 4; ++ct) {
    int col = w * 64 + ct * 16 + lr;
    float csum = 0.f;
#pragma unroll
    for (int r = 0; r < 4; ++r) {
      int row = l0 + sg * 4 + r;
      float v = accg[ct][r] * (1.f / H_);
      asps_mean[((long)b * L_ + row) * L_ + col] = v;
      csum += v;
    }
    // reduce the block's 16-row partial column sum over the 4 sg groups
    csum += __shfl_xor(csum, 16, 64);
    csum += __shfl_xor(csum, 32, 64);
    if (sg == 0) atomicAdd(avgH + b * L_ + col, csum * (1.f / L_));
  }
}

// ---------------- fused S-GEMM + row softmax, BK=64 chunked, dbuf, XCD-grouped -------
__global__ __launch_bounds__(256) void gemm_sfmx(
    const unsigned short* __restrict__ u1, const unsigned short* __restrict__ g1,
    unsigned short* __restrict__ P1,
    const unsigned short* __restrict__ u2, const unsigned short* __restrict__ g2,
    unsigned short* __restrict__ P2) {
  constexpr int ASH = 64 * 32;
  constexpr int CHS = ASH + 8192;   // chunk = A(64x32) + B(256x32)
  constexpr int BUFS = 2 * CHS;     // 2 chunks per buffer (BK=64)
  __shared__ alignas(16) unsigned short smem[2 * BUFS];
  __shared__ float redm[2][64];
  __shared__ float reds[2][64];
  int dtot = blockIdx.x;
  int xcd = dtot & 7, rr = dtot >> 3;
  int bm = rr & 3;
  int bz = (rr >> 2) * 8 + xcd;
  const unsigned short* Ap; const unsigned short* Bp; unsigned short* Pp;
  if (bz < 32) {
    Ap = u1 + (long)bz * L_ * MEM_; Bp = g1 + (long)bz * L_ * MEM_;
    Pp = P1 + (long)bz * L_ * L_;
  } else {
    int z = bz - 32;
    Ap = u2 + (long)z * L_ * MEM_; Bp = g2 + (long)z * L_ * MEM_;
    Pp = P2 + (long)z * L_ * L_;
  }
  const int t = threadIdx.x;
  const int l = t & 63, w = t >> 6;
  const int wr = w >> 1, wc = w & 1;
  const int lr = l & 15, sg = l >> 4;
  f32x4 acc[2][8] = {};

  const int rc = l >> 2;
  const int sslot = (l & 3) ^ ((rc >> 1) & 3);
  const unsigned short* gA = Ap + (long)(bm * 64 + w * 16 + rc) * MEM_ + sslot * 8;
  const unsigned short* gB[4];
#pragma unroll
  for (int j = 0; j < 4; ++j)
    gB[j] = Bp + (long)(w * 64 + j * 16 + rc) * MEM_ + sslot * 8;
  const int stA = w * 512;
  int stB[4];
#pragma unroll
  for (int j = 0; j < 4; ++j) stB[j] = ASH + (w * 4 + j) * 512;

  const int swz = (sg ^ ((lr >> 1) & 3)) * 8;
  int aoff[2], boff[8];
#pragma unroll
  for (int m = 0; m < 2; ++m) aoff[m] = (wr * 32 + m * 16 + lr) * 32 + swz;
#pragma unroll
  for (int n = 0; n < 8; ++n) boff[n] = ASH + (wc * 128 + n * 16 + lr) * 32 + swz;

  auto stageS = [&](int kbase, unsigned short* buf) {
#pragma unroll
    for (int c = 0; c < 2; ++c) {
      gload_lds16(gA + kbase + c * 32, buf + c * CHS + stA);
#pragma unroll
      for (int j = 0; j < 4; ++j)
        gload_lds16(gB[j] + kbase + c * 32, buf + c * CHS + stB[j]);
    }
  };

  constexpr int NT = MEM_ / 64;  // 6
  stageS(0, smem);
  for (int tt = 0; tt < NT; ++tt) {
    const int cur = (tt & 1) * BUFS;
    if (tt + 1 < NT) {
      stageS((tt + 1) * 64, smem + ((tt + 1) & 1) * BUFS);
      asm volatile("s_waitcnt vmcnt(10)" ::: "memory");
    } else {
      asm volatile("s_waitcnt vmcnt(0)" ::: "memory");
    }
    __builtin_amdgcn_s_barrier();
    asm volatile("" ::: "memory");
    bfrag8 af[2][2], bf[2][8];
#pragma unroll
    for (int c = 0; c < 2; ++c) {
#pragma unroll
      for (int m = 0; m < 2; ++m)
        af[c][m] = *(const bfrag8*)(smem + cur + c * CHS + aoff[m]);
#pragma unroll
      for (int n = 0; n < 8; ++n)
        bf[c][n] = *(const bfrag8*)(smem + cur + c * CHS + boff[n]);
    }
    __builtin_amdgcn_s_setprio(1);
#pragma unroll
    for (int c = 0; c < 2; ++c)
#pragma unroll
      for (int m = 0; m < 2; ++m)
#pragma unroll
        for (int n = 0; n < 8; ++n)
          acc[m][n] = __builtin_amdgcn_mfma_f32_16x16x32_bf16(af[c][m], bf[c][n], acc[m][n], 0, 0, 0);
    __builtin_amdgcn_s_setprio(0);
    asm volatile("" ::: "memory");
    __builtin_amdgcn_s_barrier();
    asm volatile("" ::: "memory");
  }

#pragma unroll
  for (int m = 0; m < 2; ++m) {
#pragma unroll
    for (int r = 0; r < 4; ++r) {
      int lrow = wr * 32 + m * 16 + (l >> 4) * 4 + r;
      float mx = -1e30f;
#pragma unroll
      for (int n = 0; n < 8; ++n) mx = fmaxf(mx, acc[m][n][r]);
#pragma unroll
      for (int o = 1; o < 16; o <<= 1) mx = fmaxf(mx, __shfl_xor(mx, o, 64));
      if (lr == 0) redm[wc][lrow] = mx;
    }
  }
  __syncthreads();
#pragma unroll
  for (int m = 0; m < 2; ++m) {
#pragma unroll
    for (int r = 0; r < 4; ++r) {
      int lrow = wr * 32 + m * 16 + (l >> 4) * 4 + r;
      float mx = fmaxf(redm[0][lrow], redm[1][lrow]);
      float s = 0.f;
#pragma unroll
      for (int n = 0; n < 8; ++n) {
        float e = __expf(acc[m][n][r] - mx);
        acc[m][n][r] = e;
        s += e;
      }
#pragma unroll
      for (int o = 1; o < 16; o <<= 1) s += __shfl_xor(s, o, 64);
      if (lr == 0) reds[wc][lrow] = s;
    }
  }
  __syncthreads();
#pragma unroll
  for (int m = 0; m < 2; ++m) {
#pragma unroll
    for (int r = 0; r < 4; ++r) {
      int lrow = wr * 32 + m * 16 + (l >> 4) * 4 + r;
      float inv = 1.f / (reds[0][lrow] + reds[1][lrow]);
      int row = bm * 64 + lrow;
#pragma unroll
      for (int n = 0; n < 8; ++n) {
        int col = wc * 128 + n * 16 + lr;
        Pp[(long)row * L_ + col] = f2bf(acc[m][n][r] * inv);
      }
    }
  }
}

// ---------------- fused adj combine + adj_ag + KL partials + denominators ------------
// 3-stage merged block reductions (1 barrier per stage).
__global__ __launch_bounds__(256) void adjag_kl(const float* __restrict__ part0,
                                                const float* __restrict__ part1,
                                                const float* __restrict__ srcm,
                                                const float* __restrict__ asps_mean,
                                                const float* __restrict__ avgH,
                                                const float* __restrict__ amask,
                                                const float* __restrict__ adjr,
                                                unsigned short* __restrict__ adjsbf,
                                                unsigned short* __restrict__ adjagbf,
                                                float* __restrict__ klpart,
                                                float* __restrict__ den_s,
                                                float* __restrict__ den_ag) {
  long row = blockIdx.x;               // b*L + l
  int m = threadIdx.x;
  int l = (int)(row & 255);
  int b = (int)(row >> 8);
  long idx = row * L_ + m;
  float s = (part0[idx] + part1[idx]) * (1.f / H_);
  if (m == l) s = 1.f;
  s *= srcm[b * L_ + l];
  adjsbf[idx] = f2bf(s);
  bool rowa = amask[b * L_ + l] > 0.f;
  bool cola = amask[b * L_ + m] > 0.f;
  float asa;
  if (rowa && cola) asa = (l >= m) ? avgH[b * L_ + m] : avgH[b * L_ + l];
  else if (rowa)    asa = avgH[b * L_ + m];
  else if (cola)    asa = avgH[b * L_ + l];
  else              asa = asps_mean[idx];
  float r = (asa > 0.25f) ? 1.f : expf(adjr[idx]);
  float a = r * asa;
  adjagbf[idx] = f2bf(a);

  __shared__ float redA[4][4];
  __shared__ float redB[4][2];
  __shared__ float redC[4];
  int w = m >> 6;
  float v0 = s, v1 = a, v2 = s, v3 = a;
#pragma unroll
  for (int o = 32; o; o >>= 1) {
    v0 += __shfl_xor(v0, o, 64);
    v1 += __shfl_xor(v1, o, 64);
    v2 = fmaxf(v2, __shfl_xor(v2, o, 64));
    v3 = fmaxf(v3, __shfl_xor(v3, o, 64));
  }
  if ((m & 63) == 0) {
    redA[w][0] = v0; redA[w][1] = v1; redA[w][2] = v2; redA[w][3] = v3;
  }
  __syncthreads();
  float sum_s = redA[0][0] + redA[1][0] + redA[2][0] + redA[3][0];
  float sum_a = redA[0][1] + redA[1][1] + redA[2][1] + redA[3][1];
  float mx_s = fmaxf(fmaxf(redA[0][2], redA[1][2]), fmaxf(redA[2][2], redA[3][2]));
  float mx_a = fmaxf(fmaxf(redA[0][3], redA[1][3]), fmaxf(redA[2][3], redA[3][3]));
  float es = expf(s - mx_s), ea = expf(a - mx_a);
  float t0 = es, t1 = ea;
#pragma unroll
  for (int o = 32; o; o >>= 1) {
    t0 += __shfl_xor(t0, o, 64);
    t1 += __shfl_xor(t1, o, 64);
  }
  if ((m & 63) == 0) { redB[w][0] = t0; redB[w][1] = t1; }
  __syncthreads();
  float ses = redB[0][0] + redB[1][0] + redB[2][0] + redB[3][0];
  float sea = redB[0][1] + redB[1][1] + redB[2][1] + redB[3][1];
  float logq = (s - mx_s) - logf(ses);
  float logp = (a - mx_a) - logf(sea);
  float term = (es / ses) * (logq - logp);
#pragma unroll
  for (int o = 32; o; o >>= 1) term += __shfl_xor(term, o, 64);
  if ((m & 63) == 0) redC[w] = term;
  __syncthreads();
  if (m == 0) {
    klpart[row] = redC[0] + redC[1] + redC[2] + redC[3];
    den_s[row] = sum_s + 1.f;
    den_ag[row] = sum_a + 1.f;
  }
}

// ---------------- classifier head (+ KL finish at blockIdx == B_) ----------------
__global__ __launch_bounds__(256) void final_kernel(const unsigned short* __restrict__ o_ag,
                                                    const unsigned short* __restrict__ o_s,
                                                    const float* __restrict__ pooled,
                                                    const float* __restrict__ amask,
                                                    const float* __restrict__ wc,
                                                    const float* __restrict__ bc,
                                                    const float* __restrict__ klpart,
                                                    float* __restrict__ dout) {
  int b = blockIdx.x, t = threadIdx.x;
  __shared__ float red[4];
  if (b == B_) {  // KL finish
    float s = 0.f;
    for (int i = t; i < B_ * L_; i += 256) s += klpart[i];
    s = blkRedSum(s, red);
    if (t == 0) dout[96] = expf(-s * 0.1f);
    return;
  }
  __shared__ float cS[1536];
  __shared__ float maskS[256];
  maskS[t] = amask[b * L_ + t];
  float wn = blkRedSum(maskS[t], red);
  for (int e = t; e < MEM_; e += 256) {
    float s1 = 0.f, s2 = 0.f;
    for (int l = 0; l < L_; ++l) {
      float mk = maskS[l];
      if (mk != 0.f) {
        s1 += mk * bf2f(o_ag[((long)b * L_ + l) * MEM_ + e]);
        s2 += mk * bf2f(o_s[((long)b * L_ + l) * MEM_ + e]);
      }
    }
    cS[e] = s1 / wn;
    cS[MEM_ + e] = s2 / wn;
  }
  for (int j = t; j < D_; j += 256) cS[2 * MEM_ + j] = pooled[b * D_ + j];
  __syncthreads();
  float p0 = 0.f, p1 = 0.f, p2 = 0.f;
  for (int j = t; j < 1536; j += 256) {
    float v = cS[j];
    p0 += v * wc[j * 3 + 0];
    p1 += v * wc[j * 3 + 1];
    p2 += v * wc[j * 3 + 2];
  }
  p0 = blkRedSum(p0, red);
  p1 = blkRedSum(p1, red);
  p2 = blkRedSum(p2, red);
  if (t == 0) {
    dout[b * 3 + 0] = p0 + bc[0];
    dout[b * 3 + 1] = p1 + bc[1];
    dout[b * 3 + 2] = p2 + bc[2];
  }
}

extern "C" void kernel_launch(void* const* d_in, const int* in_sizes, int n_in,
                              void* d_out, int out_size, void* d_ws, size_t ws_size,
                              hipStream_t stream) {
  const float* seq    = (const float*)d_in[0];
  const float* pooled = (const float*)d_in[1];
  const float* adjr   = (const float*)d_in[2];
  const float* srcm   = (const float*)d_in[3];
  const float* amask  = (const float*)d_in[4];
  const float* ln_g   = (const float*)d_in[5];
  const float* ln_b   = (const float*)d_in[6];
  const float* wq     = (const float*)d_in[7];
  const float* bq     = (const float*)d_in[8];
  const float* wk     = (const float*)d_in[9];
  const float* bk     = (const float*)d_in[10];
  const float* wd     = (const float*)d_in[11];
  const float* bd     = (const float*)d_in[12];
  const float* wm     = (const float*)d_in[13];
  const float* bm     = (const float*)d_in[14];
  const float* wa0    = (const float*)d_in[15];
  const float* ba0    = (const float*)d_in[16];
  const float* wa1    = (const float*)d_in[17];
  const float* ba1    = (const float*)d_in[18];
  const float* ws0    = (const float*)d_in[19];
  const float* bs0    = (const float*)d_in[20];
  const float* ws1    = (const float*)d_in[21];
  const float* bs1    = (const float*)d_in[22];
  const float* aff1   = (const float*)d_in[23];
  const float* aff2   = (const float*)d_in[24];
  const float* wc     = (const float*)d_in[25];
  const float* bc     = (const float*)d_in[26];

  float* ws = (float*)d_ws;
  float* S0 = ws;
  float* S1 = S0 + 6291456;
  float* S2 = S1 + 3145728;
  float* S3 = S2 + 3145728;
  float* S4 = S3 + 3145728;
  float* S5 = S4 + 524288;
  float* part0  = S5 + 2097152;
  float* part1  = part0 + 2097152;
  unsigned short* adjsbf  = (unsigned short*)(part1 + 2097152);
  unsigned short* adjagbf = adjsbf + 2097152;
  unsigned short* wT      = adjagbf + 2097152;
  unsigned short* wqT   = wT;
  unsigned short* wkT   = wT + 589824;
  unsigned short* wa0T  = wT + 1179648;
  unsigned short* ws0T  = wT + 1474560;
  unsigned short* wa1T  = wT + 1769472;
  unsigned short* ws1T  = wT + 1916928;
  unsigned short* aff1T = wT + 2064384;
  unsigned short* aff2T = wT + 2211840;
  float* tail   = (float*)(wT + 2359296);
  float* avgH   = tail;
  float* den_s  = avgH + 8192;
  float* den_ag = den_s + 8192;
  float* klp    = den_ag + 8192;

  unsigned short* o_agbf = (unsigned short*)S0;
  unsigned short* o_sbf  = o_agbf + 3145728;
  unsigned short* gTag   = o_agbf + 6291456;
  unsigned short* gTs    = o_agbf + 9437184;
  unsigned short* xbf    = (unsigned short*)S1;
  unsigned short* qbf    = (unsigned short*)S2;
  unsigned short* g_agbf = (unsigned short*)S2;
  unsigned short* g_sbf  = g_agbf + 3145728;
  unsigned short* kbf    = (unsigned short*)S3;
  unsigned short* tTag   = (unsigned short*)S3;
  unsigned short* tTs    = tTag + 3145728;
  unsigned short* u1bf   = (unsigned short*)S3;
  unsigned short* u2bf   = u1bf + 3145728;
  unsigned short* aspbf  = (unsigned short*)S4;
  unsigned short* wdT    = aspbf + 524288;
  unsigned short* wmT    = wdT + 49152;
  float* asps = S5;
  unsigned short* P1bf = (unsigned short*)S5;
  unsigned short* P2bf = P1bf + 2097152;
  float* dout = (float*)d_out;

  const long sAdjSh = (long)L_ * L_;
  const long sMemSh = (long)L_ * MEM_;

  hipMemsetAsync(avgH, 0, B_ * L_ * sizeof(float), stream);
  prep_kernel<<<600 + B_ * L_, 256, 0, stream>>>(
      seq, ln_g, ln_b, xbf, wq, wqT, wk, wkT, wa0, wa0T, ws0, ws0T,
      wa1, wa1T, ws1, ws1T, aff1, aff1T, aff2, aff2T, wd, wdT, wm, wmT);
  // paired q/k projections: MR=128, BK=32 (KCH=1 — verified optimum), XCD-grouped by bm
  gemm_bb<128, 1><<<768, 256, 0, stream>>>(
      xbf, wqT, nullptr, qbf, nullptr, 8192, 768, 768, 0, 0, 0, 0, bq, nullptr, 0,
      xbf, wkT, nullptr, kbf, nullptr, bk, nullptr, 1, 6, 2, 0);
  attn_asp<<<1536, 256, 0, stream>>>(qbf, kbf, srcm, part0, part1,
                                     xbf, wdT, amask, bd, aspbf);
  // fused asp@Wm + asps_mean + avgH partials (replaces asp_wm_v2 + asps_mean_v2 + avgh)
  asp_wm_mean<<<B_ * 16, 256, 0, stream>>>(aspbf, wmT, kbf, bm, asps, avgH);
  adjag_kl<<<B_ * L_, 256, 0, stream>>>(part0, part1, srcm, asps, avgH, amask, adjr,
                                        adjsbf, adjagbf, klp, den_s, den_ag);

  for (int li = 0; li < 2; ++li) {
    int Kd = li ? MEM_ : D_;
    const unsigned short* inag = li ? o_agbf : xbf;
    const unsigned short* ins  = li ? o_sbf : xbf;
    const unsigned short* wAT = li ? wa1T : wa0T;
    const float* bA = li ? ba1 : ba0;
    const unsigned short* wST = li ? ws1T : ws0T;
    const float* bS = li ? bs1 : bs0;
    // t-GEMMs: BK=64, grouped by bm
    gemm_bb<64, 2><<<768, 256, 0, stream>>>(
        inag, wAT, nullptr, nullptr, tTag, 8192, MEM_, Kd, 0, 0, 0, sMemSh,
        nullptr, nullptr, 0,
        ins, wST, nullptr, nullptr, tTs, nullptr, nullptr, 1, 3, 2, 0);
    // g-GEMMs: BK=64, grouped by bz
    gemm_bb<64, 2><<<768, 256, 0, stream>>>(
        adjagbf, tTag, nullptr, g_agbf, gTag, L_, MEM_, L_, sAdjSh, sMemSh, sMemSh,
        sMemSh, bA, den_ag, 1,
        adjsbf, tTs, nullptr, g_sbf, gTs, bS, den_s, 32, 3, 4, 1);
    // u-GEMMs: BK=64, grouped by bm
    gemm_bb<64, 2><<<768, 256, 0, stream>>>(
        g_agbf, aff1T, nullptr, u1bf, nullptr, 8192, MEM_, MEM_, 0, 0, 0, 0,
        nullptr, nullptr, 0,
        g_sbf, aff2T, nullptr, u2bf, nullptr, nullptr, nullptr, 1, 3, 2, 0);
    // fused S+softmax: BK=64, XCD-grouped by z
    gemm_sfmx<<<256, 256, 0, stream>>>(u1bf, g_sbf, P1bf, u2bf, g_agbf, P2bf);
    // PV: BK=64, grouped by bz
    gemm_bb<64, 2><<<768, 256, 0, stream>>>(
        P1bf, gTs, nullptr, o_agbf, nullptr, L_, MEM_, L_, sAdjSh, sMemSh, sMemSh, 0,
        nullptr, nullptr, 0,
        P2bf, gTag, nullptr, o_sbf, nullptr, nullptr, nullptr, 32, 3, 4, 1);
  }

  final_kernel<<<B_ + 1, 256, 0, stream>>>(o_agbf, o_sbf, pooled, amask, wc, bc,
                                           klp, dout);
}

// Round 27
// 347.859 us; speedup vs baseline: 1.0388x; 1.0388x over previous
//
#include <hip/hip_runtime.h>

#define B_ 32
#define L_ 256
#define D_ 768
#define H_ 12
#define DK_ 64
#define MEM_ 384

typedef __attribute__((ext_vector_type(8))) short bfrag8;    // 8 bf16 (4 VGPRs)
typedef __attribute__((ext_vector_type(8))) unsigned short us8;
typedef __attribute__((ext_vector_type(4))) float f32x4;

__device__ inline unsigned short f2bf(float f) {
  unsigned u = __float_as_uint(f);
  return (unsigned short)((u + 0x7fffu + ((u >> 16) & 1u)) >> 16);
}
__device__ inline float bf2f(unsigned short u) {
  return __uint_as_float(((unsigned)u) << 16);
}
__device__ inline float tanh_fast(float x) {
  x = fminf(fmaxf(x, -30.f), 30.f);
  float e = __expf(2.f * x);
  return (e - 1.f) * __builtin_amdgcn_rcpf(e + 1.f);
}
__device__ inline void gload_lds16(const unsigned short* g, unsigned short* l) {
  __builtin_amdgcn_global_load_lds(
      (__attribute__((address_space(1))) void*)(g),
      (__attribute__((address_space(3))) void*)(l), 16, 0, 0);
}

// ---------------- block reduce helpers ----------------
__device__ inline float waveRedSum(float v) {
#pragma unroll
  for (int o = 32; o; o >>= 1) v += __shfl_xor(v, o, 64);
  return v;
}
__device__ inline float blkRedSum(float v, float* red) {
  v = waveRedSum(v);
  int w = threadIdx.x >> 6;
  __syncthreads();
  if ((threadIdx.x & 63) == 0) red[w] = v;
  __syncthreads();
  return red[0] + red[1] + red[2] + red[3];
}

// ---------------- prep: all weight transposes (blocks 0..599) + LayerNorm (600+) -----
// (fp32 x output removed — dead store; only xbf is consumed downstream)
__global__ __launch_bounds__(256) void prep_kernel(
    const float* __restrict__ seq, const float* __restrict__ lng,
    const float* __restrict__ lnb,
    unsigned short* __restrict__ xbf,
    const float* __restrict__ wq, unsigned short* __restrict__ wqT,
    const float* __restrict__ wk, unsigned short* __restrict__ wkT,
    const float* __restrict__ wa0, unsigned short* __restrict__ wa0T,
    const float* __restrict__ ws0, unsigned short* __restrict__ ws0T,
    const float* __restrict__ wa1, unsigned short* __restrict__ wa1T,
    const float* __restrict__ ws1, unsigned short* __restrict__ ws1T,
    const float* __restrict__ aff1, unsigned short* __restrict__ aff1T,
    const float* __restrict__ aff2, unsigned short* __restrict__ aff2T,
    const float* __restrict__ wd, unsigned short* __restrict__ wdT,
    const float* __restrict__ wm, unsigned short* __restrict__ wmT) {
  int bid = blockIdx.x;
  if (bid >= 600) {  // ---- LayerNorm row ----
    long row = bid - 600;
    const float* p = seq + row * D_;
    float v[3];
#pragma unroll
    for (int i = 0; i < 3; ++i) v[i] = p[threadIdx.x + i * 256];
    __shared__ float red[4];
    float s = v[0] + v[1] + v[2];
    s = blkRedSum(s, red);
    float mu = s * (1.f / D_);
    float ss = 0.f;
#pragma unroll
    for (int i = 0; i < 3; ++i) { float d = v[i] - mu; ss += d * d; }
    ss = blkRedSum(ss, red);
    float sd = sqrtf(ss * (1.f / (D_ - 1)));
    float inv = 1.f / (sd + 1e-6f);
#pragma unroll
    for (int i = 0; i < 3; ++i) {
      int c = threadIdx.x + i * 256;
      float o = lng[c] * (v[i] - mu) * inv + lnb[c];
      xbf[row * D_ + c] = f2bf(o);
    }
    return;
  }
  const float* src; unsigned short* dst; int Rr, Cc, tIdx;
  if (bid < 144)      { src = wq;   dst = wqT;   Rr = 768; Cc = 768; tIdx = bid; }
  else if (bid < 288) { src = wk;   dst = wkT;   Rr = 768; Cc = 768; tIdx = bid - 144; }
  else if (bid < 360) { src = wa0;  dst = wa0T;  Rr = 768; Cc = 384; tIdx = bid - 288; }
  else if (bid < 432) { src = ws0;  dst = ws0T;  Rr = 768; Cc = 384; tIdx = bid - 360; }
  else if (bid < 468) { src = wa1;  dst = wa1T;  Rr = 384; Cc = 384; tIdx = bid - 432; }
  else if (bid < 504) { src = ws1;  dst = ws1T;  Rr = 384; Cc = 384; tIdx = bid - 468; }
  else if (bid < 540) { src = aff1; dst = aff1T; Rr = 384; Cc = 384; tIdx = bid - 504; }
  else if (bid < 576) { src = aff2; dst = aff2T; Rr = 384; Cc = 384; tIdx = bid - 540; }
  else if (bid < 588) { src = wd;   dst = wdT;   Rr = 768; Cc = 64;  tIdx = bid - 576; }
  else { int h = bid - 588; src = wm + h * 4096; dst = wmT + h * 4096; Rr = 64; Cc = 64; tIdx = 0; }
  __shared__ float tile[64][65];
  int nx = Cc >> 6;
  int c0 = (tIdx % nx) * 64, r0 = (tIdx / nx) * 64;
  int tx = threadIdx.x & 63, ty = threadIdx.x >> 6;
#pragma unroll
  for (int i = 0; i < 16; ++i)
    tile[ty + i * 4][tx] = src[(long)(r0 + ty + i * 4) * Cc + c0 + tx];
  __syncthreads();
#pragma unroll
  for (int i = 0; i < 16; ++i)
    dst[(long)(c0 + ty + i * 4) * Rr + r0 + tx] = f2bf(tile[tx][ty + i * 4]);
}

// ---------------- all-bf16 MFMA GEMM, DMA staging, BK=32*KCH, dbuf + counted vmcnt ---
// KCH k-chunks per buffer. 1D grid with XCD-aware remap (gmode 0: group by bm; 1: by bz).
template <int MR, int KCH>
__global__ __launch_bounds__(256) void gemm_bb(
    const unsigned short* __restrict__ A, const unsigned short* __restrict__ Bt,
    float* __restrict__ C, unsigned short* __restrict__ Cbf,
    unsigned short* __restrict__ CT,
    int M, int N, int K, long sA, long sB, long sC, long sCT,
    const float* __restrict__ bias, const float* __restrict__ rowDiv, int relu,
    const unsigned short* __restrict__ A2, const unsigned short* __restrict__ Bt2,
    float* __restrict__ C2, unsigned short* __restrict__ Cbf2,
    unsigned short* __restrict__ CT2,
    const float* __restrict__ bias2, const float* __restrict__ rowDiv2, int zsplit,
    int GX, int GZ, int gmode) {
  constexpr int MFRAG = MR / 32;
  constexpr int RW = MR / 2;
  constexpr int ASH = MR * 32;
  constexpr int CHS = ASH + 4096;
  constexpr int BUFS = KCH * CHS;
  constexpr int TSH = 64 * (MR + 8);
  constexpr int SMN = (2 * BUFS > TSH) ? 2 * BUFS : TSH;
  constexpr int LPI = KCH * (MR / 64 + 2);  // loads per iteration
  __shared__ alignas(16) unsigned short smem[SMN];
  const int tid = threadIdx.x;
  int dtot = blockIdx.x;
  int xcd = dtot & 7, rrg = dtot >> 3;
  int bn, bm, bz;
  if (gmode == 0) {
    int gsz = GX * GZ;
    int ul = rrg / gsz, j = rrg % gsz;
    bm = ul * 8 + xcd;
    bz = j / GX;
    bn = j % GX;
  } else {
    int gsz2 = GX * GZ;   // GZ carries bm-count here
    int ul = rrg / gsz2, j = rrg % gsz2;
    bz = ul * 8 + xcd;
    bm = j / GX;
    bn = j % GX;
  }
  const unsigned short* Ap = A; const unsigned short* Btp = Bt;
  float* Cp = C; unsigned short* Cbp = Cbf; unsigned short* CTp = CT;
  const float* biasp = bias; const float* rowDivp = rowDiv;
  if (zsplit > 0 && bz >= zsplit) {
    bz -= zsplit;
    Ap = A2; Btp = Bt2; Cp = C2; Cbp = Cbf2; CTp = CT2; biasp = bias2; rowDivp = rowDiv2;
  }
  Ap += (long)bz * sA; Btp += (long)bz * sB;
  if (Cp) Cp += (long)bz * sC;
  if (Cbp) Cbp += (long)bz * sC;
  if (CTp) CTp += (long)bz * sCT;

  f32x4 acc[MFRAG][4] = {};
  const int l = tid & 63, w = tid >> 6;
  const int wr = w >> 1, wc = w & 1;
  const int lr = l & 15, sg = l >> 4;

  const int rc = l >> 2;
  const int sslot = (l & 3) ^ ((rc >> 1) & 3);
  const unsigned short* gA0 = Ap + (long)(bm * MR + w * 16 + rc) * K + sslot * 8;
  const unsigned short* gA1 = (MR == 128)
      ? Ap + (long)(bm * MR + (w + 4) * 16 + rc) * K + sslot * 8 : nullptr;
  const unsigned short* gB0 = Btp + (long)(bn * 128 + w * 16 + rc) * K + sslot * 8;
  const unsigned short* gB1 = Btp + (long)(bn * 128 + (w + 4) * 16 + rc) * K + sslot * 8;
  const int stA0 = w * 512, stA1 = (w + 4) * 512;
  const int stB0 = ASH + w * 512, stB1 = ASH + (w + 4) * 512;

  const int swz = (sg ^ ((lr >> 1) & 3)) * 8;
  int aoff[MFRAG], boff[4];
#pragma unroll
  for (int m = 0; m < MFRAG; ++m) aoff[m] = (wr * RW + m * 16 + lr) * 32 + swz;
#pragma unroll
  for (int n = 0; n < 4; ++n) boff[n] = ASH + (wc * 64 + n * 16 + lr) * 32 + swz;

  auto stage = [&](int kbase, unsigned short* buf) {
#pragma unroll
    for (int c = 0; c < KCH; ++c) {
      gload_lds16(gA0 + kbase + c * 32, buf + c * CHS + stA0);
      if (MR == 128) gload_lds16(gA1 + kbase + c * 32, buf + c * CHS + stA1);
      gload_lds16(gB0 + kbase + c * 32, buf + c * CHS + stB0);
      gload_lds16(gB1 + kbase + c * 32, buf + c * CHS + stB1);
    }
  };

  const int nt = K / (32 * KCH);
  stage(0, smem);

  for (int t = 0; t < nt; ++t) {
    const int cur = (t & 1) * BUFS;
    if (t + 1 < nt) {
      stage((t + 1) * (32 * KCH), smem + ((t + 1) & 1) * BUFS);
      if constexpr (LPI == 3)
        asm volatile("s_waitcnt vmcnt(3)" ::: "memory");
      else if constexpr (LPI == 4)
        asm volatile("s_waitcnt vmcnt(4)" ::: "memory");
      else if constexpr (LPI == 6)
        asm volatile("s_waitcnt vmcnt(6)" ::: "memory");
      else
        asm volatile("s_waitcnt vmcnt(8)" ::: "memory");
    } else {
      asm volatile("s_waitcnt vmcnt(0)" ::: "memory");
    }
    __builtin_amdgcn_s_barrier();
    asm volatile("" ::: "memory");
    bfrag8 af[KCH][MFRAG], bf[KCH][4];
#pragma unroll
    for (int c = 0; c < KCH; ++c) {
#pragma unroll
      for (int m = 0; m < MFRAG; ++m)
        af[c][m] = *(const bfrag8*)(smem + cur + c * CHS + aoff[m]);
#pragma unroll
      for (int n = 0; n < 4; ++n)
        bf[c][n] = *(const bfrag8*)(smem + cur + c * CHS + boff[n]);
    }
    __builtin_amdgcn_s_setprio(1);
#pragma unroll
    for (int c = 0; c < KCH; ++c)
#pragma unroll
      for (int m = 0; m < MFRAG; ++m)
#pragma unroll
        for (int n = 0; n < 4; ++n)
          acc[m][n] = __builtin_amdgcn_mfma_f32_16x16x32_bf16(af[c][m], bf[c][n], acc[m][n], 0, 0, 0);
    __builtin_amdgcn_s_setprio(0);
    asm volatile("" ::: "memory");
    __builtin_amdgcn_s_barrier();
    asm volatile("" ::: "memory");
  }

  if (Cp || Cbp) {
#pragma unroll
    for (int m = 0; m < MFRAG; ++m) {
#pragma unroll
      for (int r = 0; r < 4; ++r) {
        int row = bm * MR + wr * RW + m * 16 + (l >> 4) * 4 + r;
        float rd = rowDivp ? 1.f / rowDivp[(long)bz * M + row] : 1.f;
#pragma unroll
        for (int n = 0; n < 4; ++n) {
          int col = bn * 128 + wc * 64 + n * 16 + lr;
          float v = acc[m][n][r];
          if (biasp) v += biasp[col];
          v *= rd;
          if (relu) v = fmaxf(v, 0.f);
          if (Cp) Cp[(long)row * N + col] = v;
          if (Cbp) Cbp[(long)row * N + col] = f2bf(v);
        }
      }
    }
  }
  if (CT) {
    auto Ts = (unsigned short(*)[MR + 8])smem;
#pragma unroll
    for (int ch = 0; ch < 2; ++ch) {
      __syncthreads();
      if (wc == ch) {
#pragma unroll
        for (int m = 0; m < MFRAG; ++m) {
#pragma unroll
          for (int r = 0; r < 4; ++r) {
            int rowl = wr * RW + m * 16 + (l >> 4) * 4 + r;
            float rd = rowDivp ? 1.f / rowDivp[(long)bz * M + bm * MR + rowl] : 1.f;
#pragma unroll
            for (int n = 0; n < 4; ++n) {
              int col = bn * 128 + wc * 64 + n * 16 + lr;
              float v = acc[m][n][r];
              if (biasp) v += biasp[col];
              v *= rd;
              if (relu) v = fmaxf(v, 0.f);
              Ts[n * 16 + lr][rowl] = f2bf(v);
            }
          }
        }
      }
      __syncthreads();
      int trow = tid >> 2, tc = (tid & 3) * (MR / 4);
      int colg = bn * 128 + ch * 64 + trow;
      int rowg = bm * MR + tc;
      unsigned short* dp = CTp + (long)(rowg >> 8) * sCT + (long)colg * 256 + (rowg & 255);
#pragma unroll
      for (int j = 0; j < MR / 32; ++j)
        *(us8*)(dp + j * 8) = *(const us8*)&Ts[trow][tc + j * 8];
    }
  }
}

// ---------------- attention halves (0..1023, XCD-grouped, no-max softmax,
//                  next-pair k/q prefetched under softmax tail) + asp (1024..1535) ----
__global__ __launch_bounds__(256) void attn_asp(
    const unsigned short* __restrict__ qbf, const unsigned short* __restrict__ kbf,
    const float* __restrict__ srcm,
    float* __restrict__ part0, float* __restrict__ part1,
    const unsigned short* __restrict__ xbf, const unsigned short* __restrict__ wdT,
    const float* __restrict__ amask, const float* __restrict__ bd,
    unsigned short* __restrict__ aspbf) {
  int t = threadIdx.x;
  int w = t >> 6, l = t & 63;
  int lr = l & 15, kg = (l >> 4) * 8;
  if (blockIdx.x >= 1024) {  // ---- asp projection ----
    int l0 = (blockIdx.x - 1024) << 4;
    const unsigned short* ap = xbf + (long)(l0 + lr) * D_ + kg;
    const unsigned short* bp = wdT + (long)(w * 16 + lr) * D_ + kg;
    f32x4 acc = {};
#pragma unroll
    for (int k0 = 0; k0 < D_; k0 += 32) {
      bfrag8 af = *(const bfrag8*)(ap + k0);
      bfrag8 bf = *(const bfrag8*)(bp + k0);
      acc = __builtin_amdgcn_mfma_f32_16x16x32_bf16(af, bf, acc, 0, 0, 0);
    }
    int col = w * 16 + lr;
#pragma unroll
    for (int r = 0; r < 4; ++r) {
      int row = l0 + (l >> 4) * 4 + r;
      float v = acc[r] * amask[row] + bd[col];
      aspbf[(long)row * DK_ + col] = f2bf(v);
    }
    return;
  }
  int d = blockIdx.x;
  int b = (d & 7) + 8 * ((d >> 3) & 3);
  int rest = d >> 5;
  int l0 = (rest & 15) << 4;
  int half = rest >> 4;
  int rbase = (l >> 4) * 4;
  __shared__ float red[3][2][16][4];
  float acc[4][4] = {};
  float cmv[4];
#pragma unroll
  for (int ct = 0; ct < 4; ++ct) cmv[ct] = srcm[b * L_ + w * 64 + ct * 16 + lr];

  const int hp0 = half * 3;
  const long qrow = (long)b * L_ + l0 + lr;
  const unsigned short* apq = qbf + qrow * D_ + hp0 * 128 + kg;
  bfrag8 a00 = *(const bfrag8*)apq;
  bfrag8 a01 = *(const bfrag8*)(apq + 32);
  bfrag8 a10 = *(const bfrag8*)(apq + 64);
  bfrag8 a11 = *(const bfrag8*)(apq + 96);
  bfrag8 kv[4][4];
#pragma unroll
  for (int ct = 0; ct < 4; ++ct) {
    const unsigned short* bp =
        kbf + ((long)b * L_ + w * 64 + ct * 16 + lr) * D_ + hp0 * 128 + kg;
    kv[ct][0] = *(const bfrag8*)bp;
    kv[ct][1] = *(const bfrag8*)(bp + 32);
    kv[ct][2] = *(const bfrag8*)(bp + 64);
    kv[ct][3] = *(const bfrag8*)(bp + 96);
  }

#pragma unroll 1
  for (int ph = 0; ph < 3; ++ph) {
    float sv0[4][4], sv1[4][4];
#pragma unroll
    for (int ct = 0; ct < 4; ++ct) {
      f32x4 c0 = {}, c1 = {};
      c0 = __builtin_amdgcn_mfma_f32_16x16x32_bf16(a00, kv[ct][0], c0, 0, 0, 0);
      c0 = __builtin_amdgcn_mfma_f32_16x16x32_bf16(a01, kv[ct][1], c0, 0, 0, 0);
      c1 = __builtin_amdgcn_mfma_f32_16x16x32_bf16(a10, kv[ct][2], c1, 0, 0, 0);
      c1 = __builtin_amdgcn_mfma_f32_16x16x32_bf16(a11, kv[ct][3], c1, 0, 0, 0);
#pragma unroll
      for (int r = 0; r < 4; ++r) { sv0[ct][r] = c0[r]; sv1[ct][r] = c1[r]; }
    }
    if (ph < 2) {
      const unsigned short* apn = qbf + qrow * D_ + (hp0 + ph + 1) * 128 + kg;
      a00 = *(const bfrag8*)apn;
      a01 = *(const bfrag8*)(apn + 32);
      a10 = *(const bfrag8*)(apn + 64);
      a11 = *(const bfrag8*)(apn + 96);
#pragma unroll
      for (int ct = 0; ct < 4; ++ct) {
        const unsigned short* bp =
            kbf + ((long)b * L_ + w * 64 + ct * 16 + lr) * D_ + (hp0 + ph + 1) * 128 + kg;
        kv[ct][0] = *(const bfrag8*)bp;
        kv[ct][1] = *(const bfrag8*)(bp + 32);
        kv[ct][2] = *(const bfrag8*)(bp + 64);
        kv[ct][3] = *(const bfrag8*)(bp + 96);
      }
    }
#pragma unroll
    for (int ct = 0; ct < 4; ++ct) {
      bool msk = (cmv[ct] == 0.f);
#pragma unroll
      for (int r = 0; r < 4; ++r) {
        sv0[ct][r] = __expf(msk ? -1e9f : sv0[ct][r] * 0.125f);
        sv1[ct][r] = __expf(msk ? -1e9f : sv1[ct][r] * 0.125f);
      }
    }
#pragma unroll
    for (int r = 0; r < 4; ++r) {
      float s0 = sv0[0][r] + sv0[1][r] + sv0[2][r] + sv0[3][r];
      float s1 = sv1[0][r] + sv1[1][r] + sv1[2][r] + sv1[3][r];
#pragma unroll
      for (int o = 1; o < 16; o <<= 1) {
        s0 += __shfl_xor(s0, o, 64);
        s1 += __shfl_xor(s1, o, 64);
      }
      if (lr == 0) {
        red[ph][0][rbase + r][w] = s0;
        red[ph][1][rbase + r][w] = s1;
      }
    }
    __syncthreads();
#pragma unroll
    for (int r = 0; r < 4; ++r) {
      f32x4 s4 = *(const f32x4*)&red[ph][0][rbase + r][0];
      float inv0 = __builtin_amdgcn_rcpf(s4[0] + s4[1] + s4[2] + s4[3] + 1e-30f);
      f32x4 t4 = *(const f32x4*)&red[ph][1][rbase + r][0];
      float inv1 = __builtin_amdgcn_rcpf(t4[0] + t4[1] + t4[2] + t4[3] + 1e-30f);
#pragma unroll
      for (int ct = 0; ct < 4; ++ct)
        acc[ct][r] += sv0[ct][r] * inv0 + sv1[ct][r] * inv1;
    }
  }

  float* pp = half ? part1 : part0;
#pragma unroll
  for (int r = 0; r < 4; ++r) {
    int row = l0 + rbase + r;
#pragma unroll
    for (int ct = 0; ct < 4; ++ct) {
      int col = w * 64 + ct * 16 + lr;
      pp[((long)b * L_ + row) * L_ + col] = acc[ct][r];
    }
  }
}

// ---------------- tmpA[b,h] = aspbf[b] @ Wm[h], MFMA, no LDS ----------------
__global__ __launch_bounds__(256) void asp_wm_v2(const unsigned short* __restrict__ aspbf,
                                                 const unsigned short* __restrict__ wmT,
                                                 unsigned short* __restrict__ tmpA) {
  int bh = blockIdx.x;
  int b = bh / H_, h = bh % H_;
  int t = threadIdx.x;
  int w = t >> 6, l = t & 63;
  int lr = l & 15, kg = (l >> 4) * 8;
  const unsigned short* wp = wmT + h * 4096;
  f32x4 acc[4][4] = {};
#pragma unroll
  for (int ks = 0; ks < 2; ++ks) {
    int k0 = ks * 32;
    bfrag8 af[4], bf[4];
#pragma unroll
    for (int m = 0; m < 4; ++m)
      af[m] = *(const bfrag8*)(aspbf + (long)(b * L_ + w * 64 + m * 16 + lr) * DK_ + k0 + kg);
#pragma unroll
    for (int n = 0; n < 4; ++n)
      bf[n] = *(const bfrag8*)(wp + (n * 16 + lr) * 64 + k0 + kg);
#pragma unroll
    for (int m = 0; m < 4; ++m)
#pragma unroll
      for (int n = 0; n < 4; ++n)
        acc[m][n] = __builtin_amdgcn_mfma_f32_16x16x32_bf16(af[m], bf[n], acc[m][n], 0, 0, 0);
  }
#pragma unroll
  for (int m = 0; m < 4; ++m)
#pragma unroll
    for (int n = 0; n < 4; ++n)
#pragma unroll
      for (int r = 0; r < 4; ++r) {
        int row = w * 64 + m * 16 + (l >> 4) * 4 + r;
        int col = n * 16 + lr;
        tmpA[(((long)b * H_ + h) * L_ + row) * DK_ + col] = f2bf(acc[m][n][r]);
      }
}

// ---------------- fused S-GEMM + row softmax, BK=64 chunked, dbuf, XCD-grouped -------
__global__ __launch_bounds__(256) void gemm_sfmx(
    const unsigned short* __restrict__ u1, const unsigned short* __restrict__ g1,
    unsigned short* __restrict__ P1,
    const unsigned short* __restrict__ u2, const unsigned short* __restrict__ g2,
    unsigned short* __restrict__ P2) {
  constexpr int ASH = 64 * 32;
  constexpr int CHS = ASH + 8192;   // chunk = A(64x32) + B(256x32)
  constexpr int BUFS = 2 * CHS;     // 2 chunks per buffer (BK=64)
  __shared__ alignas(16) unsigned short smem[2 * BUFS];
  __shared__ float redm[2][64];
  __shared__ float reds[2][64];
  int dtot = blockIdx.x;
  int xcd = dtot & 7, rr = dtot >> 3;
  int bm = rr & 3;
  int bz = (rr >> 2) * 8 + xcd;
  const unsigned short* Ap; const unsigned short* Bp; unsigned short* Pp;
  if (bz < 32) {
    Ap = u1 + (long)bz * L_ * MEM_; Bp = g1 + (long)bz * L_ * MEM_;
    Pp = P1 + (long)bz * L_ * L_;
  } else {
    int z = bz - 32;
    Ap = u2 + (long)z * L_ * MEM_; Bp = g2 + (long)z * L_ * MEM_;
    Pp = P2 + (long)z * L_ * L_;
  }
  const int t = threadIdx.x;
  const int l = t & 63, w = t >> 6;
  const int wr = w >> 1, wc = w & 1;
  const int lr = l & 15, sg = l >> 4;
  f32x4 acc[2][8] = {};

  const int rc = l >> 2;
  const int sslot = (l & 3) ^ ((rc >> 1) & 3);
  const unsigned short* gA = Ap + (long)(bm * 64 + w * 16 + rc) * MEM_ + sslot * 8;
  const unsigned short* gB[4];
#pragma unroll
  for (int j = 0; j < 4; ++j)
    gB[j] = Bp + (long)(w * 64 + j * 16 + rc) * MEM_ + sslot * 8;
  const int stA = w * 512;
  int stB[4];
#pragma unroll
  for (int j = 0; j < 4; ++j) stB[j] = ASH + (w * 4 + j) * 512;

  const int swz = (sg ^ ((lr >> 1) & 3)) * 8;
  int aoff[2], boff[8];
#pragma unroll
  for (int m = 0; m < 2; ++m) aoff[m] = (wr * 32 + m * 16 + lr) * 32 + swz;
#pragma unroll
  for (int n = 0; n < 8; ++n) boff[n] = ASH + (wc * 128 + n * 16 + lr) * 32 + swz;

  auto stageS = [&](int kbase, unsigned short* buf) {
#pragma unroll
    for (int c = 0; c < 2; ++c) {
      gload_lds16(gA + kbase + c * 32, buf + c * CHS + stA);
#pragma unroll
      for (int j = 0; j < 4; ++j)
        gload_lds16(gB[j] + kbase + c * 32, buf + c * CHS + stB[j]);
    }
  };

  constexpr int NT = MEM_ / 64;  // 6
  stageS(0, smem);
  for (int tt = 0; tt < NT; ++tt) {
    const int cur = (tt & 1) * BUFS;
    if (tt + 1 < NT) {
      stageS((tt + 1) * 64, smem + ((tt + 1) & 1) * BUFS);
      asm volatile("s_waitcnt vmcnt(10)" ::: "memory");
    } else {
      asm volatile("s_waitcnt vmcnt(0)" ::: "memory");
    }
    __builtin_amdgcn_s_barrier();
    asm volatile("" ::: "memory");
    bfrag8 af[2][2], bf[2][8];
#pragma unroll
    for (int c = 0; c < 2; ++c) {
#pragma unroll
      for (int m = 0; m < 2; ++m)
        af[c][m] = *(const bfrag8*)(smem + cur + c * CHS + aoff[m]);
#pragma unroll
      for (int n = 0; n < 8; ++n)
        bf[c][n] = *(const bfrag8*)(smem + cur + c * CHS + boff[n]);
    }
    __builtin_amdgcn_s_setprio(1);
#pragma unroll
    for (int c = 0; c < 2; ++c)
#pragma unroll
      for (int m = 0; m < 2; ++m)
#pragma unroll
        for (int n = 0; n < 8; ++n)
          acc[m][n] = __builtin_amdgcn_mfma_f32_16x16x32_bf16(af[c][m], bf[c][n], acc[m][n], 0, 0, 0);
    __builtin_amdgcn_s_setprio(0);
    asm volatile("" ::: "memory");
    __builtin_amdgcn_s_barrier();
    asm volatile("" ::: "memory");
  }

#pragma unroll
  for (int m = 0; m < 2; ++m) {
#pragma unroll
    for (int r = 0; r < 4; ++r) {
      int lrow = wr * 32 + m * 16 + (l >> 4) * 4 + r;
      float mx = -1e30f;
#pragma unroll
      for (int n = 0; n < 8; ++n) mx = fmaxf(mx, acc[m][n][r]);
#pragma unroll
      for (int o = 1; o < 16; o <<= 1) mx = fmaxf(mx, __shfl_xor(mx, o, 64));
      if (lr == 0) redm[wc][lrow] = mx;
    }
  }
  __syncthreads();
#pragma unroll
  for (int m = 0; m < 2; ++m) {
#pragma unroll
    for (int r = 0; r < 4; ++r) {
      int lrow = wr * 32 + m * 16 + (l >> 4) * 4 + r;
      float mx = fmaxf(redm[0][lrow], redm[1][lrow]);
      float s = 0.f;
#pragma unroll
      for (int n = 0; n < 8; ++n) {
        float e = __expf(acc[m][n][r] - mx);
        acc[m][n][r] = e;
        s += e;
      }
#pragma unroll
      for (int o = 1; o < 16; o <<= 1) s += __shfl_xor(s, o, 64);
      if (lr == 0) reds[wc][lrow] = s;
    }
  }
  __syncthreads();
#pragma unroll
  for (int m = 0; m < 2; ++m) {
#pragma unroll
    for (int r = 0; r < 4; ++r) {
      int lrow = wr * 32 + m * 16 + (l >> 4) * 4 + r;
      float inv = 1.f / (reds[0][lrow] + reds[1][lrow]);
      int row = bm * 64 + lrow;
#pragma unroll
      for (int n = 0; n < 8; ++n) {
        int col = wc * 128 + n * 16 + lr;
        Pp[(long)row * L_ + col] = f2bf(acc[m][n][r] * inv);
      }
    }
  }
}

// ---------------- asps_mean via MFMA ----------------
__global__ __launch_bounds__(256) void asps_mean_v2(
    const unsigned short* __restrict__ tmpA,
    const unsigned short* __restrict__ kbf,
    const float* __restrict__ bias_m,
    float* __restrict__ asps_mean) {
  int blk = blockIdx.x;
  int b = blk >> 4, l0 = (blk & 15) << 4;
  int t = threadIdx.x;
  int w = t >> 6, l = t & 63;
  int lr = l & 15, kg = (l >> 4) * 8;
  float bm = bias_m[0];
  float accg[4][4] = {};
  for (int h = 0; h < H_; ++h) {
    const unsigned short* ap = tmpA + (((long)b * H_ + h) * L_ + l0 + lr) * 64 + kg;
    bfrag8 af0 = *(const bfrag8*)ap;
    bfrag8 af1 = *(const bfrag8*)(ap + 32);
#pragma unroll
    for (int ct = 0; ct < 4; ++ct) {
      const unsigned short* bp =
          kbf + ((long)b * L_ + w * 64 + ct * 16 + lr) * D_ + h * 64 + kg;
      bfrag8 bf0 = *(const bfrag8*)bp;
      bfrag8 bf1 = *(const bfrag8*)(bp + 32);
      f32x4 accl = {};
      accl = __builtin_amdgcn_mfma_f32_16x16x32_bf16(af0, bf0, accl, 0, 0, 0);
      accl = __builtin_amdgcn_mfma_f32_16x16x32_bf16(af1, bf1, accl, 0, 0, 0);
#pragma unroll
      for (int r = 0; r < 4; ++r) accg[ct][r] += tanh_fast(accl[r] + bm);
    }
  }
#pragma unroll
  for (int ct = 0; ct < 4; ++ct) {
    int col = w * 64 + ct * 16 + lr;
#pragma unroll
    for (int r = 0; r < 4; ++r) {
      int row = l0 + (l >> 4) * 4 + r;
      asps_mean[((long)b * L_ + row) * L_ + col] = accg[ct][r] * (1.f / H_);
    }
  }
}

// ---------------- avgH ----------------
__global__ __launch_bounds__(1024) void avgh_kernel(const float* __restrict__ asps_mean,
                                                    float* __restrict__ avgH) {
  int b = blockIdx.x;
  int m = threadIdx.x & 255, q = threadIdx.x >> 8;
  __shared__ float part[4][256];
  float s = 0.f;
  for (int l = q * 64; l < q * 64 + 64; ++l)
    s += asps_mean[((long)b * L_ + l) * L_ + m];
  part[q][m] = s;
  __syncthreads();
  if (q == 0)
    avgH[b * L_ + m] = (part[0][m] + part[1][m] + part[2][m] + part[3][m]) * (1.f / L_);
}

// ---------------- fused adj combine + adj_ag + KL partials + denominators ------------
// 3-stage merged block reductions (1 barrier per stage).
__global__ __launch_bounds__(256) void adjag_kl(const float* __restrict__ part0,
                                                const float* __restrict__ part1,
                                                const float* __restrict__ srcm,
                                                const float* __restrict__ asps_mean,
                                                const float* __restrict__ avgH,
                                                const float* __restrict__ amask,
                                                const float* __restrict__ adjr,
                                                unsigned short* __restrict__ adjsbf,
                                                unsigned short* __restrict__ adjagbf,
                                                float* __restrict__ klpart,
                                                float* __restrict__ den_s,
                                                float* __restrict__ den_ag) {
  long row = blockIdx.x;               // b*L + l
  int m = threadIdx.x;
  int l = (int)(row & 255);
  int b = (int)(row >> 8);
  long idx = row * L_ + m;
  float s = (part0[idx] + part1[idx]) * (1.f / H_);
  if (m == l) s = 1.f;
  s *= srcm[b * L_ + l];
  adjsbf[idx] = f2bf(s);
  bool rowa = amask[b * L_ + l] > 0.f;
  bool cola = amask[b * L_ + m] > 0.f;
  float asa;
  if (rowa && cola) asa = (l >= m) ? avgH[b * L_ + m] : avgH[b * L_ + l];
  else if (rowa)    asa = avgH[b * L_ + m];
  else if (cola)    asa = avgH[b * L_ + l];
  else              asa = asps_mean[idx];
  float r = (asa > 0.25f) ? 1.f : expf(adjr[idx]);
  float a = r * asa;
  adjagbf[idx] = f2bf(a);

  __shared__ float redA[4][4];
  __shared__ float redB[4][2];
  __shared__ float redC[4];
  int w = m >> 6;
  float v0 = s, v1 = a, v2 = s, v3 = a;
#pragma unroll
  for (int o = 32; o; o >>= 1) {
    v0 += __shfl_xor(v0, o, 64);
    v1 += __shfl_xor(v1, o, 64);
    v2 = fmaxf(v2, __shfl_xor(v2, o, 64));
    v3 = fmaxf(v3, __shfl_xor(v3, o, 64));
  }
  if ((m & 63) == 0) {
    redA[w][0] = v0; redA[w][1] = v1; redA[w][2] = v2; redA[w][3] = v3;
  }
  __syncthreads();
  float sum_s = redA[0][0] + redA[1][0] + redA[2][0] + redA[3][0];
  float sum_a = redA[0][1] + redA[1][1] + redA[2][1] + redA[3][1];
  float mx_s = fmaxf(fmaxf(redA[0][2], redA[1][2]), fmaxf(redA[2][2], redA[3][2]));
  float mx_a = fmaxf(fmaxf(redA[0][3], redA[1][3]), fmaxf(redA[2][3], redA[3][3]));
  float es = expf(s - mx_s), ea = expf(a - mx_a);
  float t0 = es, t1 = ea;
#pragma unroll
  for (int o = 32; o; o >>= 1) {
    t0 += __shfl_xor(t0, o, 64);
    t1 += __shfl_xor(t1, o, 64);
  }
  if ((m & 63) == 0) { redB[w][0] = t0; redB[w][1] = t1; }
  __syncthreads();
  float ses = redB[0][0] + redB[1][0] + redB[2][0] + redB[3][0];
  float sea = redB[0][1] + redB[1][1] + redB[2][1] + redB[3][1];
  float logq = (s - mx_s) - logf(ses);
  float logp = (a - mx_a) - logf(sea);
  float term = (es / ses) * (logq - logp);
#pragma unroll
  for (int o = 32; o; o >>= 1) term += __shfl_xor(term, o, 64);
  if ((m & 63) == 0) redC[w] = term;
  __syncthreads();
  if (m == 0) {
    klpart[row] = redC[0] + redC[1] + redC[2] + redC[3];
    den_s[row] = sum_s + 1.f;
    den_ag[row] = sum_a + 1.f;
  }
}

// ---------------- classifier head (+ KL finish at blockIdx == B_) ----------------
__global__ __launch_bounds__(256) void final_kernel(const unsigned short* __restrict__ o_ag,
                                                    const unsigned short* __restrict__ o_s,
                                                    const float* __restrict__ pooled,
                                                    const float* __restrict__ amask,
                                                    const float* __restrict__ wc,
                                                    const float* __restrict__ bc,
                                                    const float* __restrict__ klpart,
                                                    float* __restrict__ dout) {
  int b = blockIdx.x, t = threadIdx.x;
  __shared__ float red[4];
  if (b == B_) {  // KL finish
    float s = 0.f;
    for (int i = t; i < B_ * L_; i += 256) s += klpart[i];
    s = blkRedSum(s, red);
    if (t == 0) dout[96] = expf(-s * 0.1f);
    return;
  }
  __shared__ float cS[1536];
  __shared__ float maskS[256];
  maskS[t] = amask[b * L_ + t];
  float wn = blkRedSum(maskS[t], red);
  for (int e = t; e < MEM_; e += 256) {
    float s1 = 0.f, s2 = 0.f;
    for (int l = 0; l < L_; ++l) {
      float mk = maskS[l];
      if (mk != 0.f) {
        s1 += mk * bf2f(o_ag[((long)b * L_ + l) * MEM_ + e]);
        s2 += mk * bf2f(o_s[((long)b * L_ + l) * MEM_ + e]);
      }
    }
    cS[e] = s1 / wn;
    cS[MEM_ + e] = s2 / wn;
  }
  for (int j = t; j < D_; j += 256) cS[2 * MEM_ + j] = pooled[b * D_ + j];
  __syncthreads();
  float p0 = 0.f, p1 = 0.f, p2 = 0.f;
  for (int j = t; j < 1536; j += 256) {
    float v = cS[j];
    p0 += v * wc[j * 3 + 0];
    p1 += v * wc[j * 3 + 1];
    p2 += v * wc[j * 3 + 2];
  }
  p0 = blkRedSum(p0, red);
  p1 = blkRedSum(p1, red);
  p2 = blkRedSum(p2, red);
  if (t == 0) {
    dout[b * 3 + 0] = p0 + bc[0];
    dout[b * 3 + 1] = p1 + bc[1];
    dout[b * 3 + 2] = p2 + bc[2];
  }
}

extern "C" void kernel_launch(void* const* d_in, const int* in_sizes, int n_in,
                              void* d_out, int out_size, void* d_ws, size_t ws_size,
                              hipStream_t stream) {
  const float* seq    = (const float*)d_in[0];
  const float* pooled = (const float*)d_in[1];
  const float* adjr   = (const float*)d_in[2];
  const float* srcm   = (const float*)d_in[3];
  const float* amask  = (const float*)d_in[4];
  const float* ln_g   = (const float*)d_in[5];
  const float* ln_b   = (const float*)d_in[6];
  const float* wq     = (const float*)d_in[7];
  const float* bq     = (const float*)d_in[8];
  const float* wk     = (const float*)d_in[9];
  const float* bk     = (const float*)d_in[10];
  const float* wd     = (const float*)d_in[11];
  const float* bd     = (const float*)d_in[12];
  const float* wm     = (const float*)d_in[13];
  const float* bm     = (const float*)d_in[14];
  const float* wa0    = (const float*)d_in[15];
  const float* ba0    = (const float*)d_in[16];
  const float* wa1    = (const float*)d_in[17];
  const float* ba1    = (const float*)d_in[18];
  const float* ws0    = (const float*)d_in[19];
  const float* bs0    = (const float*)d_in[20];
  const float* ws1    = (const float*)d_in[21];
  const float* bs1    = (const float*)d_in[22];
  const float* aff1   = (const float*)d_in[23];
  const float* aff2   = (const float*)d_in[24];
  const float* wc     = (const float*)d_in[25];
  const float* bc     = (const float*)d_in[26];

  float* ws = (float*)d_ws;
  float* S0 = ws;
  float* S1 = S0 + 6291456;
  float* S2 = S1 + 3145728;
  float* S3 = S2 + 3145728;
  float* S4 = S3 + 3145728;
  float* S5 = S4 + 524288;
  float* part0  = S5 + 2097152;
  float* part1  = part0 + 2097152;
  unsigned short* adjsbf  = (unsigned short*)(part1 + 2097152);
  unsigned short* adjagbf = adjsbf + 2097152;
  unsigned short* wT      = adjagbf + 2097152;
  unsigned short* wqT   = wT;
  unsigned short* wkT   = wT + 589824;
  unsigned short* wa0T  = wT + 1179648;
  unsigned short* ws0T  = wT + 1474560;
  unsigned short* wa1T  = wT + 1769472;
  unsigned short* ws1T  = wT + 1916928;
  unsigned short* aff1T = wT + 2064384;
  unsigned short* aff2T = wT + 2211840;
  float* tail   = (float*)(wT + 2359296);
  float* avgH   = tail;
  float* den_s  = avgH + 8192;
  float* den_ag = den_s + 8192;
  float* klp    = den_ag + 8192;

  unsigned short* o_agbf = (unsigned short*)S0;
  unsigned short* o_sbf  = o_agbf + 3145728;
  unsigned short* gTag   = o_agbf + 6291456;
  unsigned short* gTs    = o_agbf + 9437184;
  unsigned short* xbf    = (unsigned short*)S1;
  unsigned short* qbf    = (unsigned short*)S2;
  unsigned short* tmpA   = (unsigned short*)S2;
  unsigned short* g_agbf = (unsigned short*)S2;
  unsigned short* g_sbf  = g_agbf + 3145728;
  unsigned short* kbf    = (unsigned short*)S3;
  unsigned short* tTag   = (unsigned short*)S3;
  unsigned short* tTs    = tTag + 3145728;
  unsigned short* u1bf   = (unsigned short*)S3;
  unsigned short* u2bf   = u1bf + 3145728;
  unsigned short* aspbf  = (unsigned short*)S4;
  unsigned short* wdT    = aspbf + 524288;
  unsigned short* wmT    = wdT + 49152;
  float* asps = S5;
  unsigned short* P1bf = (unsigned short*)S5;
  unsigned short* P2bf = P1bf + 2097152;
  float* dout = (float*)d_out;

  const long sAdjSh = (long)L_ * L_;
  const long sMemSh = (long)L_ * MEM_;

  prep_kernel<<<600 + B_ * L_, 256, 0, stream>>>(
      seq, ln_g, ln_b, xbf, wq, wqT, wk, wkT, wa0, wa0T, ws0, ws0T,
      wa1, wa1T, ws1, ws1T, aff1, aff1T, aff2, aff2T, wd, wdT, wm, wmT);
  // paired q/k projections: MR=128, BK=32 (KCH=1 — verified optimum), XCD-grouped by bm
  gemm_bb<128, 1><<<768, 256, 0, stream>>>(
      xbf, wqT, nullptr, qbf, nullptr, 8192, 768, 768, 0, 0, 0, 0, bq, nullptr, 0,
      xbf, wkT, nullptr, kbf, nullptr, bk, nullptr, 1, 6, 2, 0);
  attn_asp<<<1536, 256, 0, stream>>>(qbf, kbf, srcm, part0, part1,
                                     xbf, wdT, amask, bd, aspbf);
  asp_wm_v2<<<B_ * H_, 256, 0, stream>>>(aspbf, wmT, tmpA);
  asps_mean_v2<<<B_ * 16, 256, 0, stream>>>(tmpA, kbf, bm, asps);
  avgh_kernel<<<B_, 1024, 0, stream>>>(asps, avgH);
  adjag_kl<<<B_ * L_, 256, 0, stream>>>(part0, part1, srcm, asps, avgH, amask, adjr,
                                        adjsbf, adjagbf, klp, den_s, den_ag);

  for (int li = 0; li < 2; ++li) {
    int Kd = li ? MEM_ : D_;
    const unsigned short* inag = li ? o_agbf : xbf;
    const unsigned short* ins  = li ? o_sbf : xbf;
    const unsigned short* wAT = li ? wa1T : wa0T;
    const float* bA = li ? ba1 : ba0;
    const unsigned short* wST = li ? ws1T : ws0T;
    const float* bS = li ? bs1 : bs0;
    // t-GEMMs: BK=64, grouped by bm
    gemm_bb<64, 2><<<768, 256, 0, stream>>>(
        inag, wAT, nullptr, nullptr, tTag, 8192, MEM_, Kd, 0, 0, 0, sMemSh,
        nullptr, nullptr, 0,
        ins, wST, nullptr, nullptr, tTs, nullptr, nullptr, 1, 3, 2, 0);
    // g-GEMMs: BK=64, grouped by bz
    gemm_bb<64, 2><<<768, 256, 0, stream>>>(
        adjagbf, tTag, nullptr, g_agbf, gTag, L_, MEM_, L_, sAdjSh, sMemSh, sMemSh,
        sMemSh, bA, den_ag, 1,
        adjsbf, tTs, nullptr, g_sbf, gTs, bS, den_s, 32, 3, 4, 1);
    // u-GEMMs: BK=64, grouped by bm
    gemm_bb<64, 2><<<768, 256, 0, stream>>>(
        g_agbf, aff1T, nullptr, u1bf, nullptr, 8192, MEM_, MEM_, 0, 0, 0, 0,
        nullptr, nullptr, 0,
        g_sbf, aff2T, nullptr, u2bf, nullptr, nullptr, nullptr, 1, 3, 2, 0);
    // fused S+softmax: BK=64, XCD-grouped by z
    gemm_sfmx<<<256, 256, 0, stream>>>(u1bf, g_sbf, P1bf, u2bf, g_agbf, P2bf);
    // PV: BK=64, grouped by bz
    gemm_bb<64, 2><<<768, 256, 0, stream>>>(
        P1bf, gTs, nullptr, o_agbf, nullptr, L_, MEM_, L_, sAdjSh, sMemSh, sMemSh, 0,
        nullptr, nullptr, 0,
        P2bf, gTag, nullptr, o_sbf, nullptr, nullptr, nullptr, 32, 3, 4, 1);
  }

  final_kernel<<<B_ + 1, 256, 0, stream>>>(o_agbf, o_sbf, pooled, amask, wc, bc,
                                           klp, dout);
}